// Round 10
// baseline (30.058 us; speedup 1.0000x reference)
//
#include <hip/hip_runtime.h>
#include <stdint.h>

#define NB 32
#define NS 8192
#define ND 64
#define CHUNK 64                 // rows per chunk
#define SEGS 32                  // segments (blocks) per batch
#define SEGROWS (NS / SEGS)      // 256 rows per block
#define CPS (SEGROWS / CHUNK)    // 4 chunks per block
#define INV_T 0.125f
#define PSTRIDE 68               // m, l, pad, pad, acc[64]
#define NPART_PER_B (SEGS * 4)   // 128 wave-partials per batch

// async global->LDS 16B DMA: per-lane global src, wave-uniform LDS base
__device__ __forceinline__ void gload16(const float* g, void* lds) {
    __builtin_amdgcn_global_load_lds(
        (const __attribute__((address_space(1))) uint32_t*)g,
        (__attribute__((address_space(3))) uint32_t*)lds, 16, 0, 0);
}

// Stage one chunk's 16-row wave slice of K (4 x 1KB DMA). LDS linear; XOR
// swizzle (slot ^= row&15) applied on the GLOBAL source address.
__device__ __forceinline__ void stage_k(const float* gbase, float* ldsbase, int l) {
#pragma unroll
    for (int i = 0; i < 4; ++i) {
        const int r = i * 4 + (l >> 4);
        gload16(gbase + (size_t)r * ND + (((l & 15) ^ (r & 15)) << 2),
                (char*)ldsbase + i * 1024);
    }
}

// ---------------- Phase 1: persistent, pipelined flash attention ----------
// 1024 blocks = 4/CU (16 waves/CU). K: DMA->LDS double-buffer; V: 3-deep
// register pipeline (R8 structure). One exact-counted vmcnt per chunk.
// Wave w owns rows [w*16,w*16+16) of each chunk -> no __syncthreads.
__global__ __launch_bounds__(256, 4) void attn_p1(
    const float* __restrict__ q, const float* __restrict__ k,
    const float* __restrict__ v, float* __restrict__ attn,
    float* __restrict__ part)
{
    __shared__ float klds[2][CHUNK * ND];   // 2 x 16 KB
    __shared__ float es[4][16];

    const int blk = blockIdx.x;             // 0..1023
    const int b   = blk >> 5;               // / SEGS
    const int seg = blk & 31;
    const int tid = threadIdx.x;
    const int w   = tid >> 6;               // wave 0..3
    const int l   = tid & 63;
    const int rl  = l >> 2;                 // score row 0..15
    const int qd  = l & 3;                  // quarter (16 dims)
    const int g   = l >> 4;                 // PV group 0..3 (4 rows each)
    const int sl  = l & 15;                 // PV dim slot (4 dims)

    const size_t kb   = (size_t)b * NS * ND;
    const int    row0 = seg * SEGROWS + w * 16;   // wave's row base (chunk 0)
    const float* vw   = v + kb;

    // q quarter into registers first (oldest in vmcnt queue)
    float4 qf[4];
#pragma unroll
    for (int i = 0; i < 4; ++i)
        qf[i] = *reinterpret_cast<const float4*>(q + b * ND + qd * 16 + i * 4);
    __builtin_amdgcn_sched_barrier(0);

    // V register pipeline: 3 rotating buffers, lane owns row g*4+j, dims sl*4..+3
    float4 vbuf[3][4];
#define VLOAD(BUF, C)                                                          \
    {                                                                          \
        const size_t rb = (size_t)(row0 + (C) * CHUNK) * ND;                   \
        _Pragma("unroll")                                                      \
        for (int j = 0; j < 4; ++j)                                            \
            vbuf[BUF][j] = *reinterpret_cast<const float4*>(                   \
                vw + rb + (size_t)(g * 4 + j) * ND + sl * 4);                  \
    }

    // prologue: K0, V0, K1, V1  (16 vmcnt entries)
    stage_k(k + kb + (size_t)row0 * ND,           &klds[0][w * 1024], l);
    VLOAD(0, 0);
    stage_k(k + kb + (size_t)(row0 + CHUNK) * ND, &klds[1][w * 1024], l);
    VLOAD(1, 1);
    __builtin_amdgcn_sched_barrier(0);

    float  m_run = -1e30f, lsum = 0.f;
    float4 acc = make_float4(0.f, 0.f, 0.f, 0.f);

    // exact outstanding-entry counts: K(c),V(c) done, rest stay in flight
    const int waitn[CPS] = {8, 9, 10, 2};

#pragma unroll
    for (int c = 0; c < CPS; ++c) {
        const int bf = c & 1;

        switch (waitn[c]) {   // literal immediates for s_waitcnt
        case 8:  asm volatile("s_waitcnt vmcnt(8)"  ::: "memory"); break;
        case 9:  asm volatile("s_waitcnt vmcnt(9)"  ::: "memory"); break;
        case 10: asm volatile("s_waitcnt vmcnt(10)" ::: "memory"); break;
        default: asm volatile("s_waitcnt vmcnt(2)"  ::: "memory"); break;
        }
        __builtin_amdgcn_sched_barrier(0);

        // scores: 4 lanes per row, 4 swizzled ds_read_b128 each
        const float* kr = &klds[bf][w * 1024 + rl * 64];
        float p = 0.f;
#pragma unroll
        for (int i = 0; i < 4; ++i) {
            const int ps = ((qd * 4 + i) ^ (rl & 15)) << 2;
            const float4 kv = *reinterpret_cast<const float4*>(kr + ps);
            p += kv.x * qf[i].x + kv.y * qf[i].y + kv.z * qf[i].z + kv.w * qf[i].w;
        }
        p += __shfl_xor(p, 1);
        p += __shfl_xor(p, 2);            // 4 lanes of each row hold full dot
        const float s = p * INV_T;

        // online softmax (wave-wide running max)
        float pmax = s;
        pmax = fmaxf(pmax, __shfl_xor(pmax, 4));
        pmax = fmaxf(pmax, __shfl_xor(pmax, 8));
        pmax = fmaxf(pmax, __shfl_xor(pmax, 16));
        pmax = fmaxf(pmax, __shfl_xor(pmax, 32));
        const float mnew  = fmaxf(m_run, pmax);
        const float scale = __expf(m_run - mnew);
        m_run = mnew;
        const float e = __expf(s - m_run);
        lsum = lsum * scale + 0.25f * e;   // each row counted by 4 lanes
        acc.x *= scale; acc.y *= scale; acc.z *= scale; acc.w *= scale;
        if (qd == 0) es[w][rl] = e;

        // PV from registers: group g rows g*4..g*4+3, lane owns 4 dims
#pragma unroll
        for (int j = 0; j < 4; ++j) {
            const float ej = es[w][g * 4 + j];
            const float4 vv = vbuf[c % 3][j];
            acc.x += ej * vv.x; acc.y += ej * vv.y;
            acc.z += ej * vv.z; acc.w += ej * vv.w;
        }

        // refill: K(c+2) DMA into this LDS buffer, V(c+2) into reg slot
        if (c < CPS - 2) {
            asm volatile("s_waitcnt lgkmcnt(0)" ::: "memory");
            __builtin_amdgcn_sched_barrier(0);
            stage_k(k + kb + (size_t)(row0 + (c + 2) * CHUNK) * ND,
                    &klds[bf][w * 1024], l);
            VLOAD((c + 2) % 3, c + 2);
        }

        // raw score store
        if (qd == 0)
            attn[(size_t)b * NS + seg * SEGROWS + c * CHUNK + w * 16 + rl] = s;
    }

    // ---- wave totals
#pragma unroll
    for (int d = 1; d < 64; d <<= 1) lsum += __shfl_xor(lsum, d);
    acc.x += __shfl_xor(acc.x, 16); acc.y += __shfl_xor(acc.y, 16);
    acc.z += __shfl_xor(acc.z, 16); acc.w += __shfl_xor(acc.w, 16);
    acc.x += __shfl_xor(acc.x, 32); acc.y += __shfl_xor(acc.y, 32);
    acc.z += __shfl_xor(acc.z, 32); acc.w += __shfl_xor(acc.w, 32);

    float* pp = part + (size_t)(blk * 4 + w) * PSTRIDE;
    if (l == 0) { pp[0] = m_run; pp[1] = lsum; }
    if (l < 16) reinterpret_cast<float4*>(pp + 4)[sl] = acc;
}

// ---------------- Tail: fused p2+p3, redundant per-block reduction --------
// 256 blocks = 8 per batch; every block independently reduces its batch's
// 128 wave-partials (L2-hot), slice-0 writes out[b], all rescale attn slices.
__global__ __launch_bounds__(256) void attn_tail(
    const float* __restrict__ part, float* __restrict__ out,
    float* __restrict__ attn)
{
    const int b     = blockIdx.x >> 3;
    const int slice = blockIdx.x & 7;
    const int tid = threadIdx.x;
    const int w = tid >> 6;
    const int l = tid & 63;
    const float* pb = part + (size_t)b * NPART_PER_B * PSTRIDE;

    __shared__ float wm[4], wl[4], wacc[4][ND];

    float m = -1e30f;
#pragma unroll
    for (int i = 0; i < 32; ++i)
        m = fmaxf(m, pb[(w * 32 + i) * PSTRIDE]);
    if (l == 0) wm[w] = m;
    __syncthreads();
    const float M = fmaxf(fmaxf(wm[0], wm[1]), fmaxf(wm[2], wm[3]));

    float ls = 0.f, accd = 0.f;
#pragma unroll
    for (int i = 0; i < 32; ++i) {
        const float* pe = pb + (w * 32 + i) * PSTRIDE;
        const float wgt = __expf(pe[0] - M);
        ls   += pe[1] * wgt;
        accd += pe[4 + l] * wgt;
    }
    if (l == 0) wl[w] = ls;
    wacc[w][l] = accd;
    __syncthreads();

    const float invl = 1.f / (wl[0] + wl[1] + wl[2] + wl[3]);
    if (slice == 0 && w == 0)
        out[b * ND + l] =
            (wacc[0][l] + wacc[1][l] + wacc[2][l] + wacc[3][l]) * invl;

    // rescale this block's 1024-score slice (256 float4s)
    float4* ap = reinterpret_cast<float4*>(attn + (size_t)b * NS) + slice * 256;
    float4 sv = ap[tid];
    sv.x = __expf(sv.x - M) * invl;
    sv.y = __expf(sv.y - M) * invl;
    sv.z = __expf(sv.z - M) * invl;
    sv.w = __expf(sv.w - M) * invl;
    ap[tid] = sv;
}

extern "C" void kernel_launch(void* const* d_in, const int* in_sizes, int n_in,
                              void* d_out, int out_size, void* d_ws, size_t ws_size,
                              hipStream_t stream)
{
    const float* q = (const float*)d_in[0];   // [32, 64]
    const float* k = (const float*)d_in[1];   // [32, 8192, 64]
    const float* v = (const float*)d_in[2];   // [32, 8192, 64]

    float* out  = (float*)d_out;              // [32,1,64]  -> 2048 floats
    float* attn = out + NB * ND;              // [32,1,8192]-> 262144 floats

    float* part = (float*)d_ws;               // [1024*4][68]

    attn_p1<<<NB * SEGS, 256, 0, stream>>>(q, k, v, attn, part);
    attn_tail<<<NB * 8, 256, 0, stream>>>(part, out, attn);
}

// Round 12
// 29.429 us; speedup vs baseline: 1.0214x; 1.0214x over previous
//
#include <hip/hip_runtime.h>
#include <stdint.h>

#define NB 32
#define NS 8192
#define ND 64
#define CHUNK 64                 // rows per chunk
#define SEGS 16                  // segments (blocks) per batch
#define SEGROWS (NS / SEGS)      // 512 rows per block
#define CPS (SEGROWS / CHUNK)    // 8 chunks per block
#define INV_T 0.125f
#define PSTRIDE 68               // m, l, pad, pad, acc[64]
#define NPART_PER_B (SEGS * 4)   // 64 wave-partials per batch

// async global->LDS 16B DMA: per-lane global src, wave-uniform LDS base
__device__ __forceinline__ void gload16(const float* g, void* lds) {
    __builtin_amdgcn_global_load_lds(
        (const __attribute__((address_space(1))) uint32_t*)g,
        (__attribute__((address_space(3))) uint32_t*)lds, 16, 0, 0);
}

// Stage one chunk's 16-row wave slice of K (4 x 1KB DMA). LDS linear; XOR
// swizzle (slot ^= row&15) applied on the GLOBAL source address.
__device__ __forceinline__ void stage_k(const float* gbase, float* ldsbase, int l) {
#pragma unroll
    for (int i = 0; i < 4; ++i) {
        const int r = i * 4 + (l >> 4);
        gload16(gbase + (size_t)r * ND + (((l & 15) ^ (r & 15)) << 2),
                (char*)ldsbase + i * 1024);
    }
}

// ---------------- Phase 1: persistent, pipelined flash attention ----------
// 512 blocks = 2/CU. K: DMA->LDS double-buffer (scores need transposed
// access). V: 3-deep REGISTER pipeline via plain dwordx4 loads (PV access is
// lane-aligned; LDS roundtrip is overhead). One exact-counted vmcnt per
// chunk. Wave w owns rows [w*16,w*16+16) of each chunk -> no __syncthreads.
__global__ __launch_bounds__(256) void attn_p1(
    const float* __restrict__ q, const float* __restrict__ k,
    const float* __restrict__ v, float* __restrict__ attn,
    float* __restrict__ part)
{
    __shared__ float klds[2][CHUNK * ND];   // 2 x 16 KB
    __shared__ float es[4][16];

    const int blk = blockIdx.x;             // 0..511
    const int b   = blk >> 4;
    const int seg = blk & 15;
    const int tid = threadIdx.x;
    const int w   = tid >> 6;               // wave 0..3
    const int l   = tid & 63;
    const int rl  = l >> 2;                 // score row 0..15
    const int qd  = l & 3;                  // quarter (16 dims)
    const int g   = l >> 4;                 // PV group 0..3 (4 rows each)
    const int sl  = l & 15;                 // PV dim slot (4 dims)

    const size_t kb   = (size_t)b * NS * ND;
    const int    row0 = seg * SEGROWS + w * 16;   // wave's row base (chunk 0)
    const float* vw   = v + kb;

    // q quarter into registers first (oldest in vmcnt queue)
    float4 qf[4];
#pragma unroll
    for (int i = 0; i < 4; ++i)
        qf[i] = *reinterpret_cast<const float4*>(q + b * ND + qd * 16 + i * 4);
    __builtin_amdgcn_sched_barrier(0);

    // V register pipeline: 3 rotating buffers, lane owns row g*4+j, dims sl*4..+3
    float4 vbuf[3][4];
#define VLOAD(BUF, C)                                                          \
    {                                                                          \
        const size_t rb = (size_t)(row0 + (C) * CHUNK) * ND;                   \
        _Pragma("unroll")                                                      \
        for (int j = 0; j < 4; ++j)                                            \
            vbuf[BUF][j] = *reinterpret_cast<const float4*>(                   \
                vw + rb + (size_t)(g * 4 + j) * ND + sl * 4);                  \
    }

    // prologue: K0, V0, K1, V1  (16 vmcnt entries)
    stage_k(k + kb + (size_t)row0 * ND,           &klds[0][w * 1024], l);
    VLOAD(0, 0);
    stage_k(k + kb + (size_t)(row0 + CHUNK) * ND, &klds[1][w * 1024], l);
    VLOAD(1, 1);
    __builtin_amdgcn_sched_barrier(0);

    float  m_run = -1e30f, lsum = 0.f;
    float4 acc = make_float4(0.f, 0.f, 0.f, 0.f);

    // exact outstanding-entry counts so K(c),V(c) are done, rest stay in flight
    // queue/iter: K(c+2)[4] + V(c+2)[4] + store(c)[1]
    const int waitn[CPS] = {8, 9, 10, 10, 10, 10, 10, 2};

#pragma unroll
    for (int c = 0; c < CPS; ++c) {
        const int bf = c & 1;

        switch (waitn[c]) {   // literal immediates for s_waitcnt
        case 8:  asm volatile("s_waitcnt vmcnt(8)"  ::: "memory"); break;
        case 9:  asm volatile("s_waitcnt vmcnt(9)"  ::: "memory"); break;
        case 10: asm volatile("s_waitcnt vmcnt(10)" ::: "memory"); break;
        default: asm volatile("s_waitcnt vmcnt(2)"  ::: "memory"); break;
        }
        __builtin_amdgcn_sched_barrier(0);

        // scores: 4 lanes per row, 4 swizzled ds_read_b128 each
        const float* kr = &klds[bf][w * 1024 + rl * 64];
        float p = 0.f;
#pragma unroll
        for (int i = 0; i < 4; ++i) {
            const int ps = ((qd * 4 + i) ^ (rl & 15)) << 2;
            const float4 kv = *reinterpret_cast<const float4*>(kr + ps);
            p += kv.x * qf[i].x + kv.y * qf[i].y + kv.z * qf[i].z + kv.w * qf[i].w;
        }
        p += __shfl_xor(p, 1);
        p += __shfl_xor(p, 2);            // 4 lanes of each row hold full dot
        const float s = p * INV_T;

        // online softmax (wave-wide running max)
        float pmax = s;
        pmax = fmaxf(pmax, __shfl_xor(pmax, 4));
        pmax = fmaxf(pmax, __shfl_xor(pmax, 8));
        pmax = fmaxf(pmax, __shfl_xor(pmax, 16));
        pmax = fmaxf(pmax, __shfl_xor(pmax, 32));
        const float mnew  = fmaxf(m_run, pmax);
        const float scale = __expf(m_run - mnew);
        m_run = mnew;
        const float e = __expf(s - m_run);
        lsum = lsum * scale + 0.25f * e;   // each row counted by 4 lanes
        acc.x *= scale; acc.y *= scale; acc.z *= scale; acc.w *= scale;
        if (qd == 0) es[w][rl] = e;

        // PV from registers: group g rows g*4..g*4+3, lane owns 4 dims
#pragma unroll
        for (int j = 0; j < 4; ++j) {
            const float ej = es[w][g * 4 + j];
            const float4 vv = vbuf[c % 3][j];
            acc.x += ej * vv.x; acc.y += ej * vv.y;
            acc.z += ej * vv.z; acc.w += ej * vv.w;
        }

        // refill: K(c+2) DMA into this LDS buffer, V(c+2) into reg slot
        if (c < CPS - 2) {
            asm volatile("s_waitcnt lgkmcnt(0)" ::: "memory");
            __builtin_amdgcn_sched_barrier(0);
            stage_k(k + kb + (size_t)(row0 + (c + 2) * CHUNK) * ND,
                    &klds[bf][w * 1024], l);
            VLOAD((c + 2) % 3, c + 2);
        }

        // raw score store
        if (qd == 0)
            attn[(size_t)b * NS + seg * SEGROWS + c * CHUNK + w * 16 + rl] = s;
    }

    // ---- wave totals
#pragma unroll
    for (int d = 1; d < 64; d <<= 1) lsum += __shfl_xor(lsum, d);
    acc.x += __shfl_xor(acc.x, 16); acc.y += __shfl_xor(acc.y, 16);
    acc.z += __shfl_xor(acc.z, 16); acc.w += __shfl_xor(acc.w, 16);
    acc.x += __shfl_xor(acc.x, 32); acc.y += __shfl_xor(acc.y, 32);
    acc.z += __shfl_xor(acc.z, 32); acc.w += __shfl_xor(acc.w, 32);

    float* pp = part + (size_t)(blk * 4 + w) * PSTRIDE;
    if (l == 0) { pp[0] = m_run; pp[1] = lsum; }
    if (l < 16) reinterpret_cast<float4*>(pp + 4)[sl] = acc;
}

// ---------------- Tail: fused p2+p3, redundant per-block reduction --------
// 256 blocks = 8 per batch; every block independently reduces its batch's 64
// wave-partials (L2-hot), slice-0 writes out[b], all rescale attn slices.
__global__ __launch_bounds__(256) void attn_tail(
    const float* __restrict__ part, float* __restrict__ out,
    float* __restrict__ attn)
{
    const int b     = blockIdx.x >> 3;
    const int slice = blockIdx.x & 7;
    const int tid = threadIdx.x;
    const int w = tid >> 6;
    const int l = tid & 63;
    const float* pb = part + (size_t)b * NPART_PER_B * PSTRIDE;

    __shared__ float wm[4], wl[4], wacc[4][ND];

    float m = -1e30f;
#pragma unroll
    for (int i = 0; i < 16; ++i)
        m = fmaxf(m, pb[(w * 16 + i) * PSTRIDE]);
    if (l == 0) wm[w] = m;
    __syncthreads();
    const float M = fmaxf(fmaxf(wm[0], wm[1]), fmaxf(wm[2], wm[3]));

    float ls = 0.f, accd = 0.f;
#pragma unroll
    for (int i = 0; i < 16; ++i) {
        const float* pe = pb + (w * 16 + i) * PSTRIDE;
        const float wgt = __expf(pe[0] - M);
        ls   += pe[1] * wgt;
        accd += pe[4 + l] * wgt;
    }
    if (l == 0) wl[w] = ls;
    wacc[w][l] = accd;
    __syncthreads();

    const float invl = 1.f / (wl[0] + wl[1] + wl[2] + wl[3]);
    if (slice == 0 && w == 0)
        out[b * ND + l] =
            (wacc[0][l] + wacc[1][l] + wacc[2][l] + wacc[3][l]) * invl;

    // rescale this block's 1024-score slice (256 float4s)
    float4* ap = reinterpret_cast<float4*>(attn + (size_t)b * NS) + slice * 256;
    float4 sv = ap[tid];
    sv.x = __expf(sv.x - M) * invl;
    sv.y = __expf(sv.y - M) * invl;
    sv.z = __expf(sv.z - M) * invl;
    sv.w = __expf(sv.w - M) * invl;
    ap[tid] = sv;
}

extern "C" void kernel_launch(void* const* d_in, const int* in_sizes, int n_in,
                              void* d_out, int out_size, void* d_ws, size_t ws_size,
                              hipStream_t stream)
{
    const float* q = (const float*)d_in[0];   // [32, 64]
    const float* k = (const float*)d_in[1];   // [32, 8192, 64]
    const float* v = (const float*)d_in[2];   // [32, 8192, 64]

    float* out  = (float*)d_out;              // [32,1,64]  -> 2048 floats
    float* attn = out + NB * ND;              // [32,1,8192]-> 262144 floats

    float* part = (float*)d_ws;               // [512*4][68]

    attn_p1<<<NB * SEGS, 256, 0, stream>>>(q, k, v, attn, part);
    attn_tail<<<NB * 8, 256, 0, stream>>>(part, out, attn);
}